// Round 5
// baseline (167.220 us; speedup 1.0000x reference)
//
#include <hip/hip_runtime.h>
#include <climits>

#define NCLS 18
#define FLAG_CAP 1024
#define NPART 256
#define PART_BASE 16
#define FLAG_BASE (PART_BASE + NPART * 8)            // 2064 (int index)
#define FRAG_US ((FLAG_BASE + 2 * FLAG_CAP) * 2)     // 8224 (ushort index), byte off 16448 (16B aligned)
// fragment table: [fragIdx][lane][8 bf16]; fragIdx*512 + lane*8 + i
#define F_W1   0   // 4 tiles x 2 kchunks
#define F_W2   8
#define F_WSEM 16  // 2 tiles x 2 kchunks (cols >=18 zero)
#define F_W3   20  // 1 tile  x 2 kchunks (cols >=3 zero)
#define NFRAG  22

typedef short bf16x8 __attribute__((ext_vector_type(8)));
typedef float f32x4  __attribute__((ext_vector_type(4)));

__device__ __forceinline__ float elu_f(float x) {
    return x > 0.f ? x : __expf(x) - 1.f;
}

__device__ __forceinline__ short f2b(float x) {   // fp32 -> bf16 RNE
    union { float f; unsigned u; } v; v.f = x;
    unsigned r = (v.u + 0x7FFFu + ((v.u >> 16) & 1u)) >> 16;
    return (short)r;
}

__device__ __forceinline__ float wave_sum(float x) {
    #pragma unroll
    for (int o = 32; o > 0; o >>= 1) x += __shfl_xor(x, o);
    return x;
}

// blocks 0..NPART-1: coord min/max partials; block NPART: swizzle weights into bf16 MFMA B-fragments
__global__ __launch_bounds__(256)
void minmax_prep(const int* __restrict__ coords, int n,
                 const float* __restrict__ W_o1, const float* __restrict__ W_o2,
                 const float* __restrict__ W_sem, const float* __restrict__ W_o3,
                 int* __restrict__ ws, unsigned short* __restrict__ ws_us)
{
    int tid = threadIdx.x;
    if (blockIdx.x == NPART) {
        // B-frag for (fragIdx, lane, i): value = W[q*32 + (lane>>4)*8 + i][t*16 + (lane&15)]
        for (int e = tid; e < NFRAG * 512; e += 256) {
            int fragIdx = e >> 9;
            int rem = e & 511;
            int lane = rem >> 3, i = rem & 7;
            int kl = ((lane >> 4) << 3) + i;
            int c16 = lane & 15;
            float val;
            if (fragIdx < F_W2) {
                int t = fragIdx >> 1, q = fragIdx & 1;
                val = W_o1[(q * 32 + kl) * 64 + t * 16 + c16];
            } else if (fragIdx < F_WSEM) {
                int fi = fragIdx - F_W2; int t = fi >> 1, q = fi & 1;
                val = W_o2[(q * 32 + kl) * 64 + t * 16 + c16];
            } else if (fragIdx < F_W3) {
                int fi = fragIdx - F_WSEM; int t = fi >> 1, q = fi & 1;
                int col = t * 16 + c16;
                val = (col < NCLS) ? W_sem[(q * 32 + kl) * NCLS + col] : 0.f;
            } else {
                int q = (fragIdx - F_W3) & 1;
                val = (c16 < 3) ? W_o3[(q * 32 + kl) * 3 + c16] : 0.f;
            }
            ws_us[FRAG_US + e] = (unsigned short)f2b(val);
        }
        return;
    }

    __shared__ int red[4][6];
    int stride = NPART * 256;
    int mn0 = INT_MAX, mn1 = INT_MAX, mn2 = INT_MAX;
    int mx0 = INT_MIN, mx1 = INT_MIN, mx2 = INT_MIN;
    for (int i = blockIdx.x * 256 + tid; i < n; i += stride) {
        int x = coords[i * 4 + 1], y = coords[i * 4 + 2], z = coords[i * 4 + 3];
        mn0 = min(mn0, x); mx0 = max(mx0, x);
        mn1 = min(mn1, y); mx1 = max(mx1, y);
        mn2 = min(mn2, z); mx2 = max(mx2, z);
    }
    #pragma unroll
    for (int o = 32; o > 0; o >>= 1) {
        mn0 = min(mn0, __shfl_xor(mn0, o)); mx0 = max(mx0, __shfl_xor(mx0, o));
        mn1 = min(mn1, __shfl_xor(mn1, o)); mx1 = max(mx1, __shfl_xor(mx1, o));
        mn2 = min(mn2, __shfl_xor(mn2, o)); mx2 = max(mx2, __shfl_xor(mx2, o));
    }
    int wid = tid >> 6;
    if ((tid & 63) == 0) {
        red[wid][0] = mn0; red[wid][1] = mn1; red[wid][2] = mn2;
        red[wid][3] = mx0; red[wid][4] = mx1; red[wid][5] = mx2;
    }
    __syncthreads();
    if (tid == 0) {
        #pragma unroll
        for (int w = 1; w < 4; w++) {
            red[0][0] = min(red[0][0], red[w][0]);
            red[0][1] = min(red[0][1], red[w][1]);
            red[0][2] = min(red[0][2], red[w][2]);
            red[0][3] = max(red[0][3], red[w][3]);
            red[0][4] = max(red[0][4], red[w][4]);
            red[0][5] = max(red[0][5], red[w][5]);
        }
        int base = PART_BASE + blockIdx.x * 8;
        #pragma unroll
        for (int c = 0; c < 6; c++) ws[base + c] = red[0][c];
        if (blockIdx.x == 0) ws[6] = 0;
    }
}

#define LDB(fi) (*(const bf16x8*)(ws_us + FRAG_US + (((fi) << 6) + lane) * 8))

__global__ __launch_bounds__(256)
void head_main(const int* __restrict__ coords, const float* __restrict__ feats,
               const float* __restrict__ b_sem,
               const float* __restrict__ g_o1, const float* __restrict__ b_o1,
               const float* __restrict__ g_o2, const float* __restrict__ b_o2,
               const float* __restrict__ b_cls,
               int* __restrict__ ws, const unsigned short* __restrict__ ws_us,
               int n, float* __restrict__ out, float* __restrict__ voted)
{
    __shared__ float bnds[6];
    __shared__ unsigned short HT[4 * 16 * 72];   // per-wave 16x64 tile (wave-private!), row stride 72

    int tid = threadIdx.x;
    int base64 = blockIdx.x * 64;

    // ---- issue the 77 MB constant-output store stream FIRST (overlaps all compute) ----
    {
        float4* outv = (float4*)out;
        int hp = tid & 127;
        int chalf = tid >> 7;
        int p = base64 + (hp >> 1);
        int half = hp & 1;
        #pragma unroll
        for (int cc = 0; cc < 9; cc++) {
            int cls = cc * 2 + chalf;
            float4 val = half ? make_float4(1.f, 1.f, 1.f, b_cls[cls])
                              : make_float4(0.f, 1.f, 1.f, 1.f);
            outv[((size_t)cls * n + p) * 2 + half] = val;
        }
    }

    // ---- wave 0: reduce NPART partials (no barrier yet — consumed at kernel end) ----
    if (tid < 64) {
        int a0 = INT_MAX, a1 = INT_MAX, a2 = INT_MAX;
        int b0 = INT_MIN, b1 = INT_MIN, b2 = INT_MIN;
        #pragma unroll
        for (int r = 0; r < 4; r++) {
            int base = PART_BASE + (tid + r * 64) * 8;
            a0 = min(a0, ws[base + 0]); a1 = min(a1, ws[base + 1]); a2 = min(a2, ws[base + 2]);
            b0 = max(b0, ws[base + 3]); b1 = max(b1, ws[base + 4]); b2 = max(b2, ws[base + 5]);
        }
        #pragma unroll
        for (int o = 32; o > 0; o >>= 1) {
            a0 = min(a0, __shfl_xor(a0, o)); a1 = min(a1, __shfl_xor(a1, o)); a2 = min(a2, __shfl_xor(a2, o));
            b0 = max(b0, __shfl_xor(b0, o)); b1 = max(b1, __shfl_xor(b1, o)); b2 = max(b2, __shfl_xor(b2, o));
        }
        if (tid == 0) {
            bnds[0] = (a0 - 1) * 0.04f; bnds[1] = (a1 - 1) * 0.04f; bnds[2] = (a2 - 1) * 0.04f;
            bnds[3] = (b0 + 1) * 0.04f; bnds[4] = (b1 + 1) * 0.04f; bnds[5] = (b2 + 1) * 0.04f;
        }
    }

    int w = tid >> 6, lane = tid & 63;
    int m = lane & 15, quad = lane >> 4;
    int wbase = w * 1152;          // w*16*72
    int q4 = quad * 4;

    // ---- A fragment of feats tile: A[m][k], k = quad*8 + i (+32 for chunk 1) ----
    const float* frow = feats + (((size_t)(base64 + w * 16 + m)) << 6) + (quad << 3);
    float4 a0 = *(const float4*)frow;
    float4 a1 = *(const float4*)(frow + 4);
    float4 a2 = *(const float4*)(frow + 32);
    float4 a3 = *(const float4*)(frow + 36);
    bf16x8 aF0, aF1;
    aF0[0]=f2b(a0.x); aF0[1]=f2b(a0.y); aF0[2]=f2b(a0.z); aF0[3]=f2b(a0.w);
    aF0[4]=f2b(a1.x); aF0[5]=f2b(a1.y); aF0[6]=f2b(a1.z); aF0[7]=f2b(a1.w);
    aF1[0]=f2b(a2.x); aF1[1]=f2b(a2.y); aF1[2]=f2b(a2.z); aF1[3]=f2b(a2.w);
    aF1[4]=f2b(a3.x); aF1[5]=f2b(a3.y); aF1[6]=f2b(a3.z); aF1[7]=f2b(a3.w);

    // ---- sem logits:  SEM = F @ Wsem  (2 j-tiles) ----
    f32x4 accS0 = {0.f,0.f,0.f,0.f}, accS1 = {0.f,0.f,0.f,0.f};
    accS0 = __builtin_amdgcn_mfma_f32_16x16x32_bf16(aF0, LDB(F_WSEM + 0), accS0, 0, 0, 0);
    accS0 = __builtin_amdgcn_mfma_f32_16x16x32_bf16(aF1, LDB(F_WSEM + 1), accS0, 0, 0, 0);
    accS1 = __builtin_amdgcn_mfma_f32_16x16x32_bf16(aF0, LDB(F_WSEM + 2), accS1, 0, 0, 0);
    accS1 = __builtin_amdgcn_mfma_f32_16x16x32_bf16(aF1, LDB(F_WSEM + 3), accS1, 0, 0, 0);

    // ---- layer 1: H = F @ W1 (4 j-tiles) ----
    f32x4 accH[4];
    #pragma unroll
    for (int t = 0; t < 4; t++) {
        f32x4 acc = {0.f,0.f,0.f,0.f};
        acc = __builtin_amdgcn_mfma_f32_16x16x32_bf16(aF0, LDB(F_W1 + t * 2 + 0), acc, 0, 0, 0);
        acc = __builtin_amdgcn_mfma_f32_16x16x32_bf16(aF1, LDB(F_W1 + t * 2 + 1), acc, 0, 0, 0);
        accH[t] = acc;
    }

    // ---- sem mask bits via ballot (class = t*16 + (lane&15), point = quad*4 + r) ----
    const float THR = -1.7346010553881064f;   // log(0.15/0.85)
    float bs0 = b_sem[m];
    int c1 = 16 + m;
    bool c1ok = (c1 < NCLS);
    float bs1 = c1ok ? b_sem[c1] : 0.f;
    unsigned long long bm0[4], bm1[4];
    #pragma unroll
    for (int r = 0; r < 4; r++) {
        bm0[r] = __ballot(accS0[r] + bs0 > THR);
        bm1[r] = __ballot(c1ok && (accS1[r] + bs1 > THR));
    }
    if (m == 0) {
        #pragma unroll
        for (int r = 0; r < 4; r++) {
            unsigned mask = (unsigned)((bm0[r] >> (quad << 4)) & 0xFFFFull)
                          | ((unsigned)((bm1[r] >> (quad << 4)) & 0x3ull) << 16);
            if (mask) {
                int slot = atomicAdd(&ws[6], 1);
                if (slot < FLAG_CAP) {
                    ws[FLAG_BASE + 2 * slot] = base64 + w * 16 + q4 + r;
                    ws[FLAG_BASE + 2 * slot + 1] = (int)mask;
                }
            }
        }
    }

    // ---- BN+ELU, store H tile (C-layout -> wave-private LDS row-major [pt][ch]) ----
    // No __syncthreads needed: each wave reads only its own slice; the compiler's
    // lgkmcnt ordering handles write->read within the wave.
    #pragma unroll
    for (int t = 0; t < 4; t++) {
        int ch = (t << 4) | m;
        float g = g_o1[ch], bb = b_o1[ch];
        #pragma unroll
        for (int r = 0; r < 4; r++) {
            float hv = elu_f(accH[t][r] * g + bb);
            HT[wbase + (q4 + r) * 72 + ch] = (unsigned short)f2b(hv);
        }
    }

    int hoff = wbase + m * 72 + (quad << 3);
    bf16x8 aH0 = *(const bf16x8*)&HT[hoff];
    bf16x8 aH1 = *(const bf16x8*)&HT[hoff + 32];

    // ---- layer 2: F2 = H @ W2 ----
    f32x4 accF[4];
    #pragma unroll
    for (int t = 0; t < 4; t++) {
        f32x4 acc = {0.f,0.f,0.f,0.f};
        acc = __builtin_amdgcn_mfma_f32_16x16x32_bf16(aH0, LDB(F_W2 + t * 2 + 0), acc, 0, 0, 0);
        acc = __builtin_amdgcn_mfma_f32_16x16x32_bf16(aH1, LDB(F_W2 + t * 2 + 1), acc, 0, 0, 0);
        accF[t] = acc;
    }

    #pragma unroll
    for (int t = 0; t < 4; t++) {
        int ch = (t << 4) | m;
        float g = g_o2[ch], bb = b_o2[ch];
        #pragma unroll
        for (int r = 0; r < 4; r++) {
            float fv = elu_f(accF[t][r] * g + bb);
            HT[wbase + (q4 + r) * 72 + ch] = (unsigned short)f2b(fv);
        }
    }

    bf16x8 aG0 = *(const bf16x8*)&HT[hoff];
    bf16x8 aG1 = *(const bf16x8*)&HT[hoff + 32];

    // ---- offset head: OFF = F2 @ W3pad (cols 0..2) ----
    f32x4 accO = {0.f,0.f,0.f,0.f};
    accO = __builtin_amdgcn_mfma_f32_16x16x32_bf16(aG0, LDB(F_W3 + 0), accO, 0, 0, 0);
    accO = __builtin_amdgcn_mfma_f32_16x16x32_bf16(aG1, LDB(F_W3 + 1), accO, 0, 0, 0);

    __syncthreads();   // only barrier: bnds (written by wave 0) consumed below

    if (m < 3) {   // lane's col = axis
        #pragma unroll
        for (int r = 0; r < 4; r++) {
            int p = base64 + w * 16 + q4 + r;
            float c = (float)coords[p * 4 + 1 + m];
            float v = fminf(fmaxf(c * 0.04f + accO[r], bnds[m]), bnds[3 + m]);
            voted[(size_t)p * 3 + m] = v;
        }
    }
}

// Rare slow path: one wave per flagged point; lane e owns channel e.
__global__ void slow_path(const float* __restrict__ feats,
                          const float* __restrict__ W_ci, const float* __restrict__ g_ci,
                          const float* __restrict__ b_ci,
                          const float* __restrict__ W_ctr, const float* __restrict__ W_reg,
                          const float* __restrict__ W_cls, const float* __restrict__ b_cls,
                          const float* __restrict__ scales,
                          const int* __restrict__ ws, int n, float* __restrict__ out)
{
    int cnt = ws[6];
    if (cnt > FLAG_CAP) cnt = FLAG_CAP;
    int lane = threadIdx.x & 63;
    int gw = (blockIdx.x * blockDim.x + threadIdx.x) >> 6;
    int nw = (gridDim.x * blockDim.x) >> 6;
    for (int i = gw; i < cnt; i += nw) {
        int npt = ws[FLAG_BASE + 2 * i];
        unsigned mb = (unsigned)ws[FLAG_BASE + 2 * i + 1];
        float fl = feats[(size_t)npt * 64 + lane];
        for (int c = 0; c < NCLS; c++) {
            if (!((mb >> c) & 1u)) continue;
            float acc = 0.f;
            for (int d = 0; d < 64; d++) {
                float fd = __shfl(fl, d);
                acc += fd * W_ci[((size_t)c * 64 + d) * 64 + lane];
            }
            float v = elu_f(acc * g_ci[c * 64 + lane] + b_ci[c * 64 + lane]);
            float ctr = wave_sum(v * W_ctr[lane]);
            float r0 = wave_sum(v * W_reg[lane * 6 + 0]);
            float r1 = wave_sum(v * W_reg[lane * 6 + 1]);
            float r2 = wave_sum(v * W_reg[lane * 6 + 2]);
            float r3 = wave_sum(v * W_reg[lane * 6 + 3]);
            float r4 = wave_sum(v * W_reg[lane * 6 + 4]);
            float r5 = wave_sum(v * W_reg[lane * 6 + 5]);
            float cl = wave_sum(v * W_cls[lane * NCLS + c]);
            if (lane == 0) {
                float sc = scales[c];
                float4* outv = (float4*)out;
                size_t idx = ((size_t)c * n + npt) * 2;
                outv[idx]     = make_float4(ctr, __expf(r0 * sc), __expf(r1 * sc), __expf(r2 * sc));
                outv[idx + 1] = make_float4(__expf(r3 * sc), __expf(r4 * sc), __expf(r5 * sc),
                                            cl + b_cls[c]);
            }
        }
    }
}

extern "C" void kernel_launch(void* const* d_in, const int* in_sizes, int n_in,
                              void* d_out, int out_size, void* d_ws, size_t ws_size,
                              hipStream_t stream) {
    const int*   coords = (const int*)  d_in[0];
    const float* feats  = (const float*)d_in[1];
    const float* W_sem  = (const float*)d_in[2];
    const float* b_sem  = (const float*)d_in[3];
    const float* W_o1   = (const float*)d_in[4];
    const float* g_o1   = (const float*)d_in[5];
    const float* b_o1   = (const float*)d_in[6];
    const float* W_o2   = (const float*)d_in[7];
    const float* g_o2   = (const float*)d_in[8];
    const float* b_o2   = (const float*)d_in[9];
    const float* W_o3   = (const float*)d_in[10];
    const float* W_ci   = (const float*)d_in[11];
    const float* g_ci   = (const float*)d_in[12];
    const float* b_ci   = (const float*)d_in[13];
    const float* W_ctr  = (const float*)d_in[14];
    const float* W_reg  = (const float*)d_in[15];
    const float* W_cls  = (const float*)d_in[16];
    const float* b_cls  = (const float*)d_in[17];
    const float* scales = (const float*)d_in[18];

    int n = in_sizes[0] / 4;
    int* ws = (int*)d_ws;
    unsigned short* ws_us = (unsigned short*)d_ws;
    float* out = (float*)d_out;
    float* voted = out + (size_t)NCLS * n * 8;

    minmax_prep<<<NPART + 1, 256, 0, stream>>>(coords, n, W_o1, W_o2, W_sem, W_o3, ws, ws_us);
    head_main<<<n / 64, 256, 0, stream>>>(
        coords, feats, b_sem, g_o1, b_o1, g_o2, b_o2, b_cls, ws, ws_us, n, out, voted);
    slow_path<<<8, 256, 0, stream>>>(
        feats, W_ci, g_ci, b_ci, W_ctr, W_reg, W_cls, b_cls, scales, ws, n, out);
}

// Round 6
// 165.708 us; speedup vs baseline: 1.0091x; 1.0091x over previous
//
#include <hip/hip_runtime.h>
#include <climits>

#define NCLS 18
#define FLAG_CAP 1024
#define NPART 256
#define PART_BASE 16
#define FLAG_BASE (PART_BASE + NPART * 8)            // 2064 (int index)
#define FRAG_US ((FLAG_BASE + 2 * FLAG_CAP) * 2)     // 8224 (ushort index), byte off 16448 (16B aligned)
// fragment table: [fragIdx][lane][8 bf16]; fragIdx*512 + lane*8 + i
#define F_W1   0   // 4 tiles x 2 kchunks
#define F_W2   8
#define F_WSEM 16  // 2 tiles x 2 kchunks (cols >=18 zero)
#define F_W3   20  // 1 tile  x 2 kchunks (cols >=3 zero)
#define NFRAG  22

typedef short bf16x8 __attribute__((ext_vector_type(8)));
typedef float f32x4  __attribute__((ext_vector_type(4)));

__device__ __forceinline__ float elu_f(float x) {
    return x > 0.f ? x : __expf(x) - 1.f;
}

__device__ __forceinline__ short f2b(float x) {   // fp32 -> bf16 RNE
    union { float f; unsigned u; } v; v.f = x;
    unsigned r = (v.u + 0x7FFFu + ((v.u >> 16) & 1u)) >> 16;
    return (short)r;
}

__device__ __forceinline__ float wave_sum(float x) {
    #pragma unroll
    for (int o = 32; o > 0; o >>= 1) x += __shfl_xor(x, o);
    return x;
}

// blocks 0..NPART-1: coord min/max partials
// block NPART: weight swizzle into bf16 MFMA B-fragments + flag-counter init
// blocks NPART+1 ...: stream the gated-off constant output (pure fill @ ~6.5 TB/s)
__global__ __launch_bounds__(256)
void combo_prep(const int* __restrict__ coords, int n,
                const float* __restrict__ W_o1, const float* __restrict__ W_o2,
                const float* __restrict__ W_sem, const float* __restrict__ W_o3,
                const float* __restrict__ b_cls,
                int* __restrict__ ws, unsigned short* __restrict__ ws_us,
                float* __restrict__ out)
{
    int tid = threadIdx.x;

    if (blockIdx.x > NPART) {
        // ---- constant-output fill: consecutive lanes -> consecutive float4 ----
        float4* outv = (float4*)out;
        int total4 = NCLS * n * 2;
        int base = (blockIdx.x - (NPART + 1)) * 2048 + tid;
        int n2 = n * 2;
        #pragma unroll
        for (int i = 0; i < 8; i++) {
            int idx = base + i * 256;
            if (idx < total4) {
                int cls = idx / n2;
                float4 v = (idx & 1) ? make_float4(1.f, 1.f, 1.f, b_cls[cls])
                                     : make_float4(0.f, 1.f, 1.f, 1.f);
                outv[idx] = v;
            }
        }
        return;
    }

    if (blockIdx.x == NPART) {
        // B-frag for (fragIdx, lane, i): value = W[q*32 + (lane>>4)*8 + i][t*16 + (lane&15)]
        for (int e = tid; e < NFRAG * 512; e += 256) {
            int fragIdx = e >> 9;
            int rem = e & 511;
            int lane = rem >> 3, i = rem & 7;
            int kl = ((lane >> 4) << 3) + i;
            int c16 = lane & 15;
            float val;
            if (fragIdx < F_W2) {
                int t = fragIdx >> 1, q = fragIdx & 1;
                val = W_o1[(q * 32 + kl) * 64 + t * 16 + c16];
            } else if (fragIdx < F_WSEM) {
                int fi = fragIdx - F_W2; int t = fi >> 1, q = fi & 1;
                val = W_o2[(q * 32 + kl) * 64 + t * 16 + c16];
            } else if (fragIdx < F_W3) {
                int fi = fragIdx - F_WSEM; int t = fi >> 1, q = fi & 1;
                int col = t * 16 + c16;
                val = (col < NCLS) ? W_sem[(q * 32 + kl) * NCLS + col] : 0.f;
            } else {
                int q = (fragIdx - F_W3) & 1;
                val = (c16 < 3) ? W_o3[(q * 32 + kl) * 3 + c16] : 0.f;
            }
            ws_us[FRAG_US + e] = (unsigned short)f2b(val);
        }
        if (tid == 0) ws[6] = 0;   // flag counter
        return;
    }

    // ---- coord min/max partial scan ----
    __shared__ int red[4][6];
    int stride = NPART * 256;
    int mn0 = INT_MAX, mn1 = INT_MAX, mn2 = INT_MAX;
    int mx0 = INT_MIN, mx1 = INT_MIN, mx2 = INT_MIN;
    for (int i = blockIdx.x * 256 + tid; i < n; i += stride) {
        int x = coords[i * 4 + 1], y = coords[i * 4 + 2], z = coords[i * 4 + 3];
        mn0 = min(mn0, x); mx0 = max(mx0, x);
        mn1 = min(mn1, y); mx1 = max(mx1, y);
        mn2 = min(mn2, z); mx2 = max(mx2, z);
    }
    #pragma unroll
    for (int o = 32; o > 0; o >>= 1) {
        mn0 = min(mn0, __shfl_xor(mn0, o)); mx0 = max(mx0, __shfl_xor(mx0, o));
        mn1 = min(mn1, __shfl_xor(mn1, o)); mx1 = max(mx1, __shfl_xor(mx1, o));
        mn2 = min(mn2, __shfl_xor(mn2, o)); mx2 = max(mx2, __shfl_xor(mx2, o));
    }
    int wid = tid >> 6;
    if ((tid & 63) == 0) {
        red[wid][0] = mn0; red[wid][1] = mn1; red[wid][2] = mn2;
        red[wid][3] = mx0; red[wid][4] = mx1; red[wid][5] = mx2;
    }
    __syncthreads();
    if (tid == 0) {
        #pragma unroll
        for (int w = 1; w < 4; w++) {
            red[0][0] = min(red[0][0], red[w][0]);
            red[0][1] = min(red[0][1], red[w][1]);
            red[0][2] = min(red[0][2], red[w][2]);
            red[0][3] = max(red[0][3], red[w][3]);
            red[0][4] = max(red[0][4], red[w][4]);
            red[0][5] = max(red[0][5], red[w][5]);
        }
        int base = PART_BASE + blockIdx.x * 8;
        #pragma unroll
        for (int c = 0; c < 6; c++) ws[base + c] = red[0][c];
    }
}

#define LDB(fi) (*(const bf16x8*)(ws_us + FRAG_US + (((fi) << 6) + lane) * 8))

__global__ __launch_bounds__(256)
void head_main(const int* __restrict__ coords, const float* __restrict__ feats,
               const float* __restrict__ b_sem,
               const float* __restrict__ g_o1, const float* __restrict__ b_o1,
               const float* __restrict__ g_o2, const float* __restrict__ b_o2,
               int* __restrict__ ws, const unsigned short* __restrict__ ws_us,
               int n, float* __restrict__ voted)
{
    __shared__ float bnds[6];
    __shared__ unsigned short HT[4 * 16 * 72];   // per-wave 16x64 tile (wave-private), row stride 72

    int tid = threadIdx.x;
    int base64 = blockIdx.x * 64;

    // ---- wave 0: reduce NPART partials (consumed after the barrier at the end) ----
    if (tid < 64) {
        int a0 = INT_MAX, a1 = INT_MAX, a2 = INT_MAX;
        int b0 = INT_MIN, b1 = INT_MIN, b2 = INT_MIN;
        #pragma unroll
        for (int r = 0; r < 4; r++) {
            int base = PART_BASE + (tid + r * 64) * 8;
            a0 = min(a0, ws[base + 0]); a1 = min(a1, ws[base + 1]); a2 = min(a2, ws[base + 2]);
            b0 = max(b0, ws[base + 3]); b1 = max(b1, ws[base + 4]); b2 = max(b2, ws[base + 5]);
        }
        #pragma unroll
        for (int o = 32; o > 0; o >>= 1) {
            a0 = min(a0, __shfl_xor(a0, o)); a1 = min(a1, __shfl_xor(a1, o)); a2 = min(a2, __shfl_xor(a2, o));
            b0 = max(b0, __shfl_xor(b0, o)); b1 = max(b1, __shfl_xor(b1, o)); b2 = max(b2, __shfl_xor(b2, o));
        }
        if (tid == 0) {
            bnds[0] = (a0 - 1) * 0.04f; bnds[1] = (a1 - 1) * 0.04f; bnds[2] = (a2 - 1) * 0.04f;
            bnds[3] = (b0 + 1) * 0.04f; bnds[4] = (b1 + 1) * 0.04f; bnds[5] = (b2 + 1) * 0.04f;
        }
    }

    int w = tid >> 6, lane = tid & 63;
    int m = lane & 15, quad = lane >> 4;
    int wbase = w * 1152;          // w*16*72
    int q4 = quad * 4;

    // ---- A fragment of feats tile: A[m][k], k = quad*8 + i (+32 for chunk 1) ----
    const float* frow = feats + (((size_t)(base64 + w * 16 + m)) << 6) + (quad << 3);
    float4 a0 = *(const float4*)frow;
    float4 a1 = *(const float4*)(frow + 4);
    float4 a2 = *(const float4*)(frow + 32);
    float4 a3 = *(const float4*)(frow + 36);

    // coords for the voted write (lanes m<3 only) — issue early to hide latency
    float cvals[4];
    if (m < 3) {
        #pragma unroll
        for (int r = 0; r < 4; r++)
            cvals[r] = (float)coords[(base64 + w * 16 + q4 + r) * 4 + 1 + m];
    }

    bf16x8 aF0, aF1;
    aF0[0]=f2b(a0.x); aF0[1]=f2b(a0.y); aF0[2]=f2b(a0.z); aF0[3]=f2b(a0.w);
    aF0[4]=f2b(a1.x); aF0[5]=f2b(a1.y); aF0[6]=f2b(a1.z); aF0[7]=f2b(a1.w);
    aF1[0]=f2b(a2.x); aF1[1]=f2b(a2.y); aF1[2]=f2b(a2.z); aF1[3]=f2b(a2.w);
    aF1[4]=f2b(a3.x); aF1[5]=f2b(a3.y); aF1[6]=f2b(a3.z); aF1[7]=f2b(a3.w);

    // ---- sem logits:  SEM = F @ Wsem  (2 j-tiles) ----
    f32x4 accS0 = {0.f,0.f,0.f,0.f}, accS1 = {0.f,0.f,0.f,0.f};
    accS0 = __builtin_amdgcn_mfma_f32_16x16x32_bf16(aF0, LDB(F_WSEM + 0), accS0, 0, 0, 0);
    accS0 = __builtin_amdgcn_mfma_f32_16x16x32_bf16(aF1, LDB(F_WSEM + 1), accS0, 0, 0, 0);
    accS1 = __builtin_amdgcn_mfma_f32_16x16x32_bf16(aF0, LDB(F_WSEM + 2), accS1, 0, 0, 0);
    accS1 = __builtin_amdgcn_mfma_f32_16x16x32_bf16(aF1, LDB(F_WSEM + 3), accS1, 0, 0, 0);

    // ---- layer 1: H = F @ W1 (4 j-tiles) ----
    f32x4 accH[4];
    #pragma unroll
    for (int t = 0; t < 4; t++) {
        f32x4 acc = {0.f,0.f,0.f,0.f};
        acc = __builtin_amdgcn_mfma_f32_16x16x32_bf16(aF0, LDB(F_W1 + t * 2 + 0), acc, 0, 0, 0);
        acc = __builtin_amdgcn_mfma_f32_16x16x32_bf16(aF1, LDB(F_W1 + t * 2 + 1), acc, 0, 0, 0);
        accH[t] = acc;
    }

    // ---- sem mask bits via ballot (class = t*16 + (lane&15), point = quad*4 + r) ----
    const float THR = -1.7346010553881064f;   // log(0.15/0.85)
    float bs0 = b_sem[m];
    int c1 = 16 + m;
    bool c1ok = (c1 < NCLS);
    float bs1 = c1ok ? b_sem[c1] : 0.f;
    unsigned long long bm0[4], bm1[4];
    #pragma unroll
    for (int r = 0; r < 4; r++) {
        bm0[r] = __ballot(accS0[r] + bs0 > THR);
        bm1[r] = __ballot(c1ok && (accS1[r] + bs1 > THR));
    }
    if (m == 0) {
        #pragma unroll
        for (int r = 0; r < 4; r++) {
            unsigned mask = (unsigned)((bm0[r] >> (quad << 4)) & 0xFFFFull)
                          | ((unsigned)((bm1[r] >> (quad << 4)) & 0x3ull) << 16);
            if (mask) {
                int slot = atomicAdd(&ws[6], 1);
                if (slot < FLAG_CAP) {
                    ws[FLAG_BASE + 2 * slot] = base64 + w * 16 + q4 + r;
                    ws[FLAG_BASE + 2 * slot + 1] = (int)mask;
                }
            }
        }
    }

    // ---- BN+ELU, store H tile (C-layout -> wave-private LDS row-major [pt][ch]) ----
    #pragma unroll
    for (int t = 0; t < 4; t++) {
        int ch = (t << 4) | m;
        float g = g_o1[ch], bb = b_o1[ch];
        #pragma unroll
        for (int r = 0; r < 4; r++) {
            float hv = elu_f(accH[t][r] * g + bb);
            HT[wbase + (q4 + r) * 72 + ch] = (unsigned short)f2b(hv);
        }
    }

    int hoff = wbase + m * 72 + (quad << 3);
    bf16x8 aH0 = *(const bf16x8*)&HT[hoff];
    bf16x8 aH1 = *(const bf16x8*)&HT[hoff + 32];

    // ---- layer 2: F2 = H @ W2 ----
    f32x4 accF[4];
    #pragma unroll
    for (int t = 0; t < 4; t++) {
        f32x4 acc = {0.f,0.f,0.f,0.f};
        acc = __builtin_amdgcn_mfma_f32_16x16x32_bf16(aH0, LDB(F_W2 + t * 2 + 0), acc, 0, 0, 0);
        acc = __builtin_amdgcn_mfma_f32_16x16x32_bf16(aH1, LDB(F_W2 + t * 2 + 1), acc, 0, 0, 0);
        accF[t] = acc;
    }

    #pragma unroll
    for (int t = 0; t < 4; t++) {
        int ch = (t << 4) | m;
        float g = g_o2[ch], bb = b_o2[ch];
        #pragma unroll
        for (int r = 0; r < 4; r++) {
            float fv = elu_f(accF[t][r] * g + bb);
            HT[wbase + (q4 + r) * 72 + ch] = (unsigned short)f2b(fv);
        }
    }

    bf16x8 aG0 = *(const bf16x8*)&HT[hoff];
    bf16x8 aG1 = *(const bf16x8*)&HT[hoff + 32];

    // ---- offset head: OFF = F2 @ W3pad (cols 0..2) ----
    f32x4 accO = {0.f,0.f,0.f,0.f};
    accO = __builtin_amdgcn_mfma_f32_16x16x32_bf16(aG0, LDB(F_W3 + 0), accO, 0, 0, 0);
    accO = __builtin_amdgcn_mfma_f32_16x16x32_bf16(aG1, LDB(F_W3 + 1), accO, 0, 0, 0);

    __syncthreads();   // only barrier: bnds (written by wave 0) consumed below

    if (m < 3) {   // lane's col = axis
        #pragma unroll
        for (int r = 0; r < 4; r++) {
            int p = base64 + w * 16 + q4 + r;
            float v = fminf(fmaxf(cvals[r] * 0.04f + accO[r], bnds[m]), bnds[3 + m]);
            voted[(size_t)p * 3 + m] = v;
        }
    }
}

// Rare slow path: one wave per flagged point; lane e owns channel e.
__global__ void slow_path(const float* __restrict__ feats,
                          const float* __restrict__ W_ci, const float* __restrict__ g_ci,
                          const float* __restrict__ b_ci,
                          const float* __restrict__ W_ctr, const float* __restrict__ W_reg,
                          const float* __restrict__ W_cls, const float* __restrict__ b_cls,
                          const float* __restrict__ scales,
                          const int* __restrict__ ws, int n, float* __restrict__ out)
{
    int cnt = ws[6];
    if (cnt > FLAG_CAP) cnt = FLAG_CAP;
    int lane = threadIdx.x & 63;
    int gw = (blockIdx.x * blockDim.x + threadIdx.x) >> 6;
    int nw = (gridDim.x * blockDim.x) >> 6;
    for (int i = gw; i < cnt; i += nw) {
        int npt = ws[FLAG_BASE + 2 * i];
        unsigned mb = (unsigned)ws[FLAG_BASE + 2 * i + 1];
        float fl = feats[(size_t)npt * 64 + lane];
        for (int c = 0; c < NCLS; c++) {
            if (!((mb >> c) & 1u)) continue;
            float acc = 0.f;
            for (int d = 0; d < 64; d++) {
                float fd = __shfl(fl, d);
                acc += fd * W_ci[((size_t)c * 64 + d) * 64 + lane];
            }
            float v = elu_f(acc * g_ci[c * 64 + lane] + b_ci[c * 64 + lane]);
            float ctr = wave_sum(v * W_ctr[lane]);
            float r0 = wave_sum(v * W_reg[lane * 6 + 0]);
            float r1 = wave_sum(v * W_reg[lane * 6 + 1]);
            float r2 = wave_sum(v * W_reg[lane * 6 + 2]);
            float r3 = wave_sum(v * W_reg[lane * 6 + 3]);
            float r4 = wave_sum(v * W_reg[lane * 6 + 4]);
            float r5 = wave_sum(v * W_reg[lane * 6 + 5]);
            float cl = wave_sum(v * W_cls[lane * NCLS + c]);
            if (lane == 0) {
                float sc = scales[c];
                float4* outv = (float4*)out;
                size_t idx = ((size_t)c * n + npt) * 2;
                outv[idx]     = make_float4(ctr, __expf(r0 * sc), __expf(r1 * sc), __expf(r2 * sc));
                outv[idx + 1] = make_float4(__expf(r3 * sc), __expf(r4 * sc), __expf(r5 * sc),
                                            cl + b_cls[c]);
            }
        }
    }
}

extern "C" void kernel_launch(void* const* d_in, const int* in_sizes, int n_in,
                              void* d_out, int out_size, void* d_ws, size_t ws_size,
                              hipStream_t stream) {
    const int*   coords = (const int*)  d_in[0];
    const float* feats  = (const float*)d_in[1];
    const float* W_sem  = (const float*)d_in[2];
    const float* b_sem  = (const float*)d_in[3];
    const float* W_o1   = (const float*)d_in[4];
    const float* g_o1   = (const float*)d_in[5];
    const float* b_o1   = (const float*)d_in[6];
    const float* W_o2   = (const float*)d_in[7];
    const float* g_o2   = (const float*)d_in[8];
    const float* b_o2   = (const float*)d_in[9];
    const float* W_o3   = (const float*)d_in[10];
    const float* W_ci   = (const float*)d_in[11];
    const float* g_ci   = (const float*)d_in[12];
    const float* b_ci   = (const float*)d_in[13];
    const float* W_ctr  = (const float*)d_in[14];
    const float* W_reg  = (const float*)d_in[15];
    const float* W_cls  = (const float*)d_in[16];
    const float* b_cls  = (const float*)d_in[17];
    const float* scales = (const float*)d_in[18];

    int n = in_sizes[0] / 4;
    int* ws = (int*)d_ws;
    unsigned short* ws_us = (unsigned short*)d_ws;
    float* out = (float*)d_out;
    float* voted = out + (size_t)NCLS * n * 8;

    int total4 = NCLS * n * 2;
    int fillb = (total4 + 2047) / 2048;
    combo_prep<<<NPART + 1 + fillb, 256, 0, stream>>>(
        coords, n, W_o1, W_o2, W_sem, W_o3, b_cls, ws, ws_us, out);
    head_main<<<n / 64, 256, 0, stream>>>(
        coords, feats, b_sem, g_o1, b_o1, g_o2, b_o2, ws, ws_us, n, voted);
    slow_path<<<8, 256, 0, stream>>>(
        feats, W_ci, g_ci, b_ci, W_ctr, W_reg, W_cls, b_cls, scales, ws, n, out);
}

// Round 7
// 165.567 us; speedup vs baseline: 1.0100x; 1.0008x over previous
//
#include <hip/hip_runtime.h>
#include <climits>

#define NCLS 18
#define NPART 256
#define PART_BASE 16
#define FRAG_US 8224   // ushort index into ws for frag table (byte off 16448, 16B aligned)
// fragment table: [fragIdx][lane][8 bf16]; fragIdx*512 + lane*8 + i
#define F_W1   0   // 4 tiles x 2 kchunks
#define F_W2   8
#define F_WSEM 16  // 2 tiles x 2 kchunks (cols >=18 zero)
#define NFRAG  20

typedef short bf16x8 __attribute__((ext_vector_type(8)));
typedef float f32x4  __attribute__((ext_vector_type(4)));

__device__ __forceinline__ float elu_f(float x) {
    return x > 0.f ? x : __expf(x) - 1.f;
}

__device__ __forceinline__ short f2b(float x) {   // fp32 -> bf16 RNE
    union { float f; unsigned u; } v; v.f = x;
    unsigned r = (v.u + 0x7FFFu + ((v.u >> 16) & 1u)) >> 16;
    return (short)r;
}

__device__ __forceinline__ float wave_sum(float x) {
    #pragma unroll
    for (int o = 32; o > 0; o >>= 1) x += __shfl_xor(x, o);
    return x;
}

// blocks 0..NPART-1: coord min/max partials; block NPART: weight swizzle
__global__ __launch_bounds__(256)
void prep(const int* __restrict__ coords, int n,
          const float* __restrict__ W_o1, const float* __restrict__ W_o2,
          const float* __restrict__ W_sem,
          int* __restrict__ ws, unsigned short* __restrict__ ws_us)
{
    int tid = threadIdx.x;

    if (blockIdx.x == NPART) {
        // B-frag for (fragIdx, lane, i): value = W[q*32 + (lane>>4)*8 + i][t*16 + (lane&15)]
        for (int e = tid; e < NFRAG * 512; e += 256) {
            int fragIdx = e >> 9;
            int rem = e & 511;
            int lane = rem >> 3, i = rem & 7;
            int kl = ((lane >> 4) << 3) + i;
            int c16 = lane & 15;
            float val;
            if (fragIdx < F_W2) {
                int t = fragIdx >> 1, q = fragIdx & 1;
                val = W_o1[(q * 32 + kl) * 64 + t * 16 + c16];
            } else if (fragIdx < F_WSEM) {
                int fi = fragIdx - F_W2; int t = fi >> 1, q = fi & 1;
                val = W_o2[(q * 32 + kl) * 64 + t * 16 + c16];
            } else {
                int fi = fragIdx - F_WSEM; int t = fi >> 1, q = fi & 1;
                int col = t * 16 + c16;
                val = (col < NCLS) ? W_sem[(q * 32 + kl) * NCLS + col] : 0.f;
            }
            ws_us[FRAG_US + e] = (unsigned short)f2b(val);
        }
        return;
    }

    // ---- coord min/max partial scan ----
    __shared__ int red[4][6];
    int stride = NPART * 256;
    int mn0 = INT_MAX, mn1 = INT_MAX, mn2 = INT_MAX;
    int mx0 = INT_MIN, mx1 = INT_MIN, mx2 = INT_MIN;
    for (int i = blockIdx.x * 256 + tid; i < n; i += stride) {
        int x = coords[i * 4 + 1], y = coords[i * 4 + 2], z = coords[i * 4 + 3];
        mn0 = min(mn0, x); mx0 = max(mx0, x);
        mn1 = min(mn1, y); mx1 = max(mx1, y);
        mn2 = min(mn2, z); mx2 = max(mx2, z);
    }
    #pragma unroll
    for (int o = 32; o > 0; o >>= 1) {
        mn0 = min(mn0, __shfl_xor(mn0, o)); mx0 = max(mx0, __shfl_xor(mx0, o));
        mn1 = min(mn1, __shfl_xor(mn1, o)); mx1 = max(mx1, __shfl_xor(mx1, o));
        mn2 = min(mn2, __shfl_xor(mn2, o)); mx2 = max(mx2, __shfl_xor(mx2, o));
    }
    int wid = tid >> 6;
    if ((tid & 63) == 0) {
        red[wid][0] = mn0; red[wid][1] = mn1; red[wid][2] = mn2;
        red[wid][3] = mx0; red[wid][4] = mx1; red[wid][5] = mx2;
    }
    __syncthreads();
    if (tid == 0) {
        #pragma unroll
        for (int w = 1; w < 4; w++) {
            red[0][0] = min(red[0][0], red[w][0]);
            red[0][1] = min(red[0][1], red[w][1]);
            red[0][2] = min(red[0][2], red[w][2]);
            red[0][3] = max(red[0][3], red[w][3]);
            red[0][4] = max(red[0][4], red[w][4]);
            red[0][5] = max(red[0][5], red[w][5]);
        }
        int base = PART_BASE + blockIdx.x * 8;
        #pragma unroll
        for (int c = 0; c < 6; c++) ws[base + c] = red[0][c];
    }
}

#define LDB(fi) (*(const bf16x8*)(ws_us + FRAG_US + (((fi) << 6) + lane) * 8))

__global__ __launch_bounds__(256)
void head_main(const int* __restrict__ coords, const float* __restrict__ feats,
               const float* __restrict__ b_sem,
               const float* __restrict__ g_o1, const float* __restrict__ b_o1,
               const float* __restrict__ g_o2, const float* __restrict__ b_o2,
               const float* __restrict__ W_o3, const float* __restrict__ b_cls,
               const float* __restrict__ W_ci, const float* __restrict__ g_ci,
               const float* __restrict__ b_ci,
               const float* __restrict__ W_ctr, const float* __restrict__ W_reg,
               const float* __restrict__ W_cls, const float* __restrict__ scales,
               const int* __restrict__ ws, const unsigned short* __restrict__ ws_us,
               int n, float* __restrict__ out, float* __restrict__ voted)
{
    __shared__ float bnds[6];
    __shared__ unsigned short HT[4 * 16 * 72];   // per-wave 16x64 tile (wave-private), stride 72

    int tid = threadIdx.x;
    int base64 = blockIdx.x * 64;
    float4* outv = (float4*)out;

    // ---- gated-off constant outputs for this block's 64 points (issue first) ----
    {
        int hp = tid & 127;
        int chalf = tid >> 7;
        int p = base64 + (hp >> 1);
        int half = hp & 1;
        #pragma unroll
        for (int cc = 0; cc < 9; cc++) {
            int cls = cc * 2 + chalf;
            float4 val = half ? make_float4(1.f, 1.f, 1.f, b_cls[cls])
                              : make_float4(0.f, 1.f, 1.f, 1.f);
            outv[((size_t)cls * n + p) * 2 + half] = val;
        }
    }

    // ---- wave 0: reduce NPART partials into bnds (consumed after the barrier) ----
    if (tid < 64) {
        int a0 = INT_MAX, a1 = INT_MAX, a2 = INT_MAX;
        int b0 = INT_MIN, b1 = INT_MIN, b2 = INT_MIN;
        #pragma unroll
        for (int r = 0; r < 4; r++) {
            int base = PART_BASE + (tid + r * 64) * 8;
            a0 = min(a0, ws[base + 0]); a1 = min(a1, ws[base + 1]); a2 = min(a2, ws[base + 2]);
            b0 = max(b0, ws[base + 3]); b1 = max(b1, ws[base + 4]); b2 = max(b2, ws[base + 5]);
        }
        #pragma unroll
        for (int o = 32; o > 0; o >>= 1) {
            a0 = min(a0, __shfl_xor(a0, o)); a1 = min(a1, __shfl_xor(a1, o)); a2 = min(a2, __shfl_xor(a2, o));
            b0 = max(b0, __shfl_xor(b0, o)); b1 = max(b1, __shfl_xor(b1, o)); b2 = max(b2, __shfl_xor(b2, o));
        }
        if (tid == 0) {
            bnds[0] = (a0 - 1) * 0.04f; bnds[1] = (a1 - 1) * 0.04f; bnds[2] = (a2 - 1) * 0.04f;
            bnds[3] = (b0 + 1) * 0.04f; bnds[4] = (b1 + 1) * 0.04f; bnds[5] = (b2 + 1) * 0.04f;
        }
    }

    int w = tid >> 6, lane = tid & 63;
    int m = lane & 15, quad = lane >> 4;
    int wbase = w * 1152;          // w*16*72
    int q4 = quad * 4;

    // ---- A fragment of feats tile: A[m][k], k = quad*8 + i (+32 for chunk 1) ----
    const float* frow = feats + (((size_t)(base64 + w * 16 + m)) << 6) + (quad << 3);
    float4 a0 = *(const float4*)frow;
    float4 a1 = *(const float4*)(frow + 4);
    float4 a2 = *(const float4*)(frow + 32);
    float4 a3 = *(const float4*)(frow + 36);

    // coords for the voted write (lanes m<3 only) — issue early
    float cvals[4];
    if (m < 3) {
        #pragma unroll
        for (int r = 0; r < 4; r++)
            cvals[r] = (float)coords[(base64 + w * 16 + q4 + r) * 4 + 1 + m];
    }

    bf16x8 aF0, aF1;
    aF0[0]=f2b(a0.x); aF0[1]=f2b(a0.y); aF0[2]=f2b(a0.z); aF0[3]=f2b(a0.w);
    aF0[4]=f2b(a1.x); aF0[5]=f2b(a1.y); aF0[6]=f2b(a1.z); aF0[7]=f2b(a1.w);
    aF1[0]=f2b(a2.x); aF1[1]=f2b(a2.y); aF1[2]=f2b(a2.z); aF1[3]=f2b(a2.w);
    aF1[4]=f2b(a3.x); aF1[5]=f2b(a3.y); aF1[6]=f2b(a3.z); aF1[7]=f2b(a3.w);

    // ---- sem logits: SEM = F @ Wsem (2 j-tiles) ----
    f32x4 accS0 = {0.f,0.f,0.f,0.f}, accS1 = {0.f,0.f,0.f,0.f};
    accS0 = __builtin_amdgcn_mfma_f32_16x16x32_bf16(aF0, LDB(F_WSEM + 0), accS0, 0, 0, 0);
    accS0 = __builtin_amdgcn_mfma_f32_16x16x32_bf16(aF1, LDB(F_WSEM + 1), accS0, 0, 0, 0);
    accS1 = __builtin_amdgcn_mfma_f32_16x16x32_bf16(aF0, LDB(F_WSEM + 2), accS1, 0, 0, 0);
    accS1 = __builtin_amdgcn_mfma_f32_16x16x32_bf16(aF1, LDB(F_WSEM + 3), accS1, 0, 0, 0);

    // ---- layer 1: H = F @ W1 (4 j-tiles) ----
    f32x4 accH[4];
    #pragma unroll
    for (int t = 0; t < 4; t++) {
        f32x4 acc = {0.f,0.f,0.f,0.f};
        acc = __builtin_amdgcn_mfma_f32_16x16x32_bf16(aF0, LDB(F_W1 + t * 2 + 0), acc, 0, 0, 0);
        acc = __builtin_amdgcn_mfma_f32_16x16x32_bf16(aF1, LDB(F_W1 + t * 2 + 1), acc, 0, 0, 0);
        accH[t] = acc;
    }

    // ---- sem mask ballots (class = t*16+m, point row = quad*4+r) ----
    const float THR = -1.7346010553881064f;   // log(0.15/0.85)
    float bs0 = b_sem[m];
    int c1 = 16 + m;
    bool c1ok = (c1 < NCLS);
    float bs1 = c1ok ? b_sem[c1] : 0.f;
    unsigned long long bm0[4], bm1[4];
    #pragma unroll
    for (int r = 0; r < 4; r++) {
        bm0[r] = __ballot(accS0[r] + bs0 > THR);
        bm1[r] = __ballot(c1ok && (accS1[r] + bs1 > THR));
    }

    // ---- BN+ELU, store H tile (C-layout -> wave-private LDS row-major [pt][ch]) ----
    #pragma unroll
    for (int t = 0; t < 4; t++) {
        int ch = (t << 4) | m;
        float g = g_o1[ch], bb = b_o1[ch];
        #pragma unroll
        for (int r = 0; r < 4; r++) {
            float hv = elu_f(accH[t][r] * g + bb);
            HT[wbase + (q4 + r) * 72 + ch] = (unsigned short)f2b(hv);
        }
    }

    int hoff = wbase + m * 72 + (quad << 3);
    bf16x8 aH0 = *(const bf16x8*)&HT[hoff];
    bf16x8 aH1 = *(const bf16x8*)&HT[hoff + 32];

    // ---- layer 2: F2 = H @ W2 ----
    f32x4 accF[4];
    #pragma unroll
    for (int t = 0; t < 4; t++) {
        f32x4 acc = {0.f,0.f,0.f,0.f};
        acc = __builtin_amdgcn_mfma_f32_16x16x32_bf16(aH0, LDB(F_W2 + t * 2 + 0), acc, 0, 0, 0);
        acc = __builtin_amdgcn_mfma_f32_16x16x32_bf16(aH1, LDB(F_W2 + t * 2 + 1), acc, 0, 0, 0);
        accF[t] = acc;
    }

    // ---- offset head in fp32 registers + shuffle reduce (no 2nd LDS round trip) ----
    float w30[4], w31[4], w32[4];
    #pragma unroll
    for (int t = 0; t < 4; t++) {
        int ch = (t << 4) | m;
        w30[t] = W_o3[ch * 3 + 0]; w31[t] = W_o3[ch * 3 + 1]; w32[t] = W_o3[ch * 3 + 2];
    }
    float offr[4][3];
    #pragma unroll
    for (int r = 0; r < 4; r++) {
        float px = 0.f, py = 0.f, pz = 0.f;
        #pragma unroll
        for (int t = 0; t < 4; t++) {
            int ch = (t << 4) | m;
            float fv = elu_f(accF[t][r] * g_o2[ch] + b_o2[ch]);
            px += fv * w30[t]; py += fv * w31[t]; pz += fv * w32[t];
        }
        #pragma unroll
        for (int o = 1; o < 16; o <<= 1) {
            px += __shfl_xor(px, o); py += __shfl_xor(py, o); pz += __shfl_xor(pz, o);
        }
        offr[r][0] = px; offr[r][1] = py; offr[r][2] = pz;
    }

    __syncthreads();   // bnds ready; also orders the constant-fill stores before slow path

    if (m < 3) {   // lane m writes axis m
        #pragma unroll
        for (int r = 0; r < 4; r++) {
            int p = base64 + w * 16 + q4 + r;
            float ov = (m == 0) ? offr[r][0] : ((m == 1) ? offr[r][1] : offr[r][2]);
            float v = fminf(fmaxf(cvals[r] * 0.04f + ov, bnds[m]), bnds[3 + m]);
            voted[(size_t)p * 3 + m] = v;
        }
    }

    // ---- in-wave rare slow path (wave-uniform branch; ~never taken) ----
    unsigned long long anyf = bm0[0] | bm0[1] | bm0[2] | bm0[3]
                            | bm1[0] | bm1[1] | bm1[2] | bm1[3];
    if (anyf != 0ull) {
        for (int qq = 0; qq < 4; qq++) {
            #pragma unroll
            for (int r = 0; r < 4; r++) {
                unsigned mask = (unsigned)((bm0[r] >> (qq << 4)) & 0xFFFFull)
                              | ((unsigned)((bm1[r] >> (qq << 4)) & 0x3ull) << 16);
                if (!mask) continue;
                int p = base64 + w * 16 + qq * 4 + r;
                float fl = feats[(size_t)p * 64 + lane];
                for (int c = 0; c < NCLS; c++) {
                    if (!((mask >> c) & 1u)) continue;
                    float acc = 0.f;
                    for (int d = 0; d < 64; d++) {
                        float fd = __shfl(fl, d);
                        acc += fd * W_ci[((size_t)c * 64 + d) * 64 + lane];
                    }
                    float v = elu_f(acc * g_ci[c * 64 + lane] + b_ci[c * 64 + lane]);
                    float ctr = wave_sum(v * W_ctr[lane]);
                    float r0 = wave_sum(v * W_reg[lane * 6 + 0]);
                    float r1 = wave_sum(v * W_reg[lane * 6 + 1]);
                    float r2 = wave_sum(v * W_reg[lane * 6 + 2]);
                    float r3 = wave_sum(v * W_reg[lane * 6 + 3]);
                    float r4 = wave_sum(v * W_reg[lane * 6 + 4]);
                    float r5 = wave_sum(v * W_reg[lane * 6 + 5]);
                    float cl = wave_sum(v * W_cls[lane * NCLS + c]);
                    if (lane == 0) {
                        float sc = scales[c];
                        size_t idx = ((size_t)c * n + p) * 2;
                        outv[idx]     = make_float4(ctr, __expf(r0 * sc), __expf(r1 * sc), __expf(r2 * sc));
                        outv[idx + 1] = make_float4(__expf(r3 * sc), __expf(r4 * sc), __expf(r5 * sc),
                                                    cl + b_cls[c]);
                    }
                }
            }
        }
    }
}

extern "C" void kernel_launch(void* const* d_in, const int* in_sizes, int n_in,
                              void* d_out, int out_size, void* d_ws, size_t ws_size,
                              hipStream_t stream) {
    const int*   coords = (const int*)  d_in[0];
    const float* feats  = (const float*)d_in[1];
    const float* W_sem  = (const float*)d_in[2];
    const float* b_sem  = (const float*)d_in[3];
    const float* W_o1   = (const float*)d_in[4];
    const float* g_o1   = (const float*)d_in[5];
    const float* b_o1   = (const float*)d_in[6];
    const float* W_o2   = (const float*)d_in[7];
    const float* g_o2   = (const float*)d_in[8];
    const float* b_o2   = (const float*)d_in[9];
    const float* W_o3   = (const float*)d_in[10];
    const float* W_ci   = (const float*)d_in[11];
    const float* g_ci   = (const float*)d_in[12];
    const float* b_ci   = (const float*)d_in[13];
    const float* W_ctr  = (const float*)d_in[14];
    const float* W_reg  = (const float*)d_in[15];
    const float* W_cls  = (const float*)d_in[16];
    const float* b_cls  = (const float*)d_in[17];
    const float* scales = (const float*)d_in[18];

    int n = in_sizes[0] / 4;
    int* ws = (int*)d_ws;
    unsigned short* ws_us = (unsigned short*)d_ws;
    float* out = (float*)d_out;
    float* voted = out + (size_t)NCLS * n * 8;

    prep<<<NPART + 1, 256, 0, stream>>>(coords, n, W_o1, W_o2, W_sem, ws, ws_us);
    head_main<<<n / 64, 256, 0, stream>>>(
        coords, feats, b_sem, g_o1, b_o1, g_o2, b_o2, W_o3, b_cls,
        W_ci, g_ci, b_ci, W_ctr, W_reg, W_cls, scales,
        ws, ws_us, n, out, voted);
}